// Round 9
// baseline (2270.864 us; speedup 1.0000x reference)
//
#include <hip/hip_runtime.h>
#include <hip/hip_bf16.h>
#include <cstdint>

// ---------------------------------------------------------------------------
// HeteroGNN: 2-layer hetero-SAGE (7 rel, 1.6M edges) + classifier, 100k nodes.
// Design C12 (= C11 + non-temporal gather streams + deg fused into binpass):
//  * [R8: 1862.4 us] Gather FETCH 1.27 GB vs 51.2 MB table matches a
//    cache-capacity model where the 179 MB/dispatch mean-WRITE stream evicts
//    table lines. Fix: NT-store mean outputs + NT-load the csr stream ->
//    streaming data stops allocating in cache, table residency rises.
//  * deg computed in binpass via global atomicAdd (deg 2.8 MB, L2 atomics);
//    deg_bucket kernel deleted (-1 dispatch, -51 MB re-read).
//  * XCD-paired GEMM column blocks kept (R8: +13 us, free).
//  * [R6 verified] merged-K GEMM per layer, adaptive slicing by grant,
//    consolidated gathers, packed binpass records.
// ---------------------------------------------------------------------------

#define NN 100000
#define NREL 7
#define NE 1600000
#define NB 128           // buckets per relation
#define BCAP 14336       // slots per bucket (mean 12500)
#define BNODES 782       // ceil(100000/128)

using uint = unsigned int;
using ushort_t = unsigned short;
using bf16x8 = __attribute__((ext_vector_type(8))) __bf16;
using f32x4 = __attribute__((ext_vector_type(4))) float;
using uintx2 = __attribute__((ext_vector_type(2))) uint;

__device__ __forceinline__ ushort_t f32_to_bf16(float f) {
    uint u = __float_as_uint(f);
    u += 0x7fffu + ((u >> 16) & 1u);
    return (ushort_t)(u >> 16);
}
__device__ __forceinline__ float bf16lo(uint u) { return __uint_as_float(u << 16); }
__device__ __forceinline__ float bf16hi(uint u) { return __uint_as_float(u & 0xffff0000u); }

// async global->LDS, 16B per lane; LDS dest = wave-uniform base + lane*16
__device__ __forceinline__ void gload16(const ushort_t* g, ushort_t* l) {
    __builtin_amdgcn_global_load_lds(
        (const __attribute__((address_space(1))) uint*)g,
        (__attribute__((address_space(3))) uint*)l, 16, 0, 0);
}

// ---------------- CSR build: pass 1 — LDS bucket binning + deg -------------
// Packed record: (src << 10) | dstlocal   (src < 2^17, dstlocal < 782 < 2^10)
// deg[] computed here via global atomicAdd (deg 2.8 MB -> L2-resident RMW).
__global__ __launch_bounds__(256) void binpass_k(const int* __restrict__ edges,
                                                 int* __restrict__ bcnt,
                                                 uint* __restrict__ bpack,
                                                 int* __restrict__ deg) {
    __shared__ int cnt[NB];
    __shared__ int lofs[NB];
    __shared__ int gbase[NB];
    __shared__ int wtot[2];
    __shared__ int stotal;
    __shared__ uint stage[4096];
    __shared__ unsigned char bb[4096];
    int r = blockIdx.y;
    int t = threadIdx.x;
    if (t < NB) cnt[t] = 0;
    __syncthreads();
    int e0 = blockIdx.x * 4096;
    uint mypack[16];
    int myrb[16];
#pragma unroll
    for (int i = 0; i < 16; ++i) {
        int e = e0 + i * 256 + t;
        if (e < NE) {
            int s = edges[(size_t)(2 * r) * NE + e];
            int d = edges[(size_t)(2 * r + 1) * NE + e];
            int b = d / BNODES;
            int dl = d - b * BNODES;
            int rank = atomicAdd(&cnt[b], 1);
            myrb[i] = (rank << 7) | b;
            mypack[i] = ((uint)s << 10) | (uint)dl;
            atomicAdd(&deg[r * NN + d], 1);
        } else {
            myrb[i] = -1;
        }
    }
    __syncthreads();
    {
        int c = (t < NB) ? cnt[t] : 0;
        int lane = t & 63, wv = t >> 6;
        int x = c;
#pragma unroll
        for (int off = 1; off < 64; off <<= 1) {
            int y = __shfl_up(x, off);
            if (lane >= off) x += y;
        }
        if (t < NB && lane == 63) wtot[wv] = x;
        __syncthreads();
        if (t < NB) {
            int excl = x - c + (wv ? wtot[0] : 0);
            lofs[t] = excl;
            gbase[t] = atomicAdd(&bcnt[r * NB + t], c);
            if (t == NB - 1) stotal = excl + c;
        }
    }
    __syncthreads();
#pragma unroll
    for (int i = 0; i < 16; ++i) {
        if (myrb[i] >= 0) {
            int b = myrb[i] & 127;
            int p = lofs[b] + (myrb[i] >> 7);
            stage[p] = mypack[i];
            bb[p] = (unsigned char)b;
        }
    }
    __syncthreads();
    int total = stotal;
    for (int p = t; p < total; p += 256) {
        int b = bb[p];
        uint pr = stage[p];
        int gpos = gbase[b] + (p - lofs[b]);
        if (gpos < BCAP) {
            bpack[((size_t)r * NB + b) * BCAP + gpos] = pr;
        }
    }
}

// ---------------- CSR build: scan (deg -> rowptr) ----------------
__global__ void scan1_k(const int* __restrict__ deg, int* __restrict__ rowptr,
                        int* __restrict__ blk, int total) {
    __shared__ int wsum[4];
    int t = threadIdx.x;
    int base = blockIdx.x * 4096 + t * 16;
    int vals[16];
    int s = 0;
#pragma unroll
    for (int i = 0; i < 16; ++i) {
        int g = base + i;
        int v = (g < total) ? deg[g] : 0;
        vals[i] = s;
        s += v;
    }
    int lane = t & 63, w = t >> 6;
    int x = s;
    for (int off = 1; off < 64; off <<= 1) {
        int y = __shfl_up(x, off);
        if (lane >= off) x += y;
    }
    if (lane == 63) wsum[w] = x;
    __syncthreads();
    if (t == 0) {
        int a = 0;
#pragma unroll
        for (int k = 0; k < 4; ++k) { int b = wsum[k]; wsum[k] = a; a += b; }
        blk[blockIdx.x] = a;
    }
    __syncthreads();
    int excl = x - s + wsum[w];
#pragma unroll
    for (int i = 0; i < 16; ++i) {
        int g = base + i;
        if (g < total) rowptr[g] = excl + vals[i];
    }
}

__global__ void scan2_k(int* blk, int nb) {
    if (threadIdx.x == 0 && blockIdx.x == 0) {
        int a = 0;
        for (int i = 0; i < nb; ++i) { int b = blk[i]; blk[i] = a; a += b; }
    }
}

__global__ void scan3_k(int* __restrict__ rowptr, const int* __restrict__ blk, int total) {
    int t = threadIdx.x;
    int add = blk[blockIdx.x];
    int base = blockIdx.x * 4096 + t * 16;
#pragma unroll
    for (int i = 0; i < 16; ++i) {
        int g = base + i;
        if (g < total) rowptr[g] += add;
    }
}

// ---------------- CSR build: per-bucket LDS counting sort ------------------
__global__ __launch_bounds__(1024) void bucket_sort_k(const uint* __restrict__ bpack,
                                                      const int* __restrict__ bcnt,
                                                      const int* __restrict__ rowptr,
                                                      int* __restrict__ csr) {
    __shared__ int stage[BCAP];
    __shared__ int lcur[BNODES];
    int rb = blockIdx.x;
    int r = rb >> 7, b = rb & 127;
    int node0 = b * BNODES;
    int nnodes = NN - node0 < BNODES ? NN - node0 : BNODES;
    int t = threadIdx.x;
    int rowbase = rowptr[r * NN + node0];
    int endIdx = r * NN + node0 + nnodes;
    int rowend = (endIdx < NREL * NN) ? rowptr[endIdx] : (NREL * NE);
    int truen = rowend - rowbase;
    int nent = truen < BCAP ? truen : BCAP;
    for (int i = t; i < nent; i += 1024) stage[i] = 0;
    for (int i = t; i < nnodes; i += 1024) lcur[i] = 0;
    __syncthreads();
    int cb = bcnt[rb];
    if (cb > BCAP) cb = BCAP;
    for (int i = t; i < cb; i += 1024) {
        uint v = bpack[(size_t)rb * BCAP + i];
        int nl = (int)(v & 1023u);
        int sv = (int)(v >> 10);
        int pos = rowptr[r * NN + node0 + nl] - rowbase + atomicAdd(&lcur[nl], 1);
        if (pos < BCAP) stage[pos] = sv;
    }
    __syncthreads();
    for (int i = t; i < nent; i += 1024) csr[rowbase + i] = stage[i];
    for (int i = nent + t; i < truen; i += 1024) csr[rowbase + i] = 0;
}

// ---------------- conversions / weight prep ----------------
__global__ void convert_x_k(const float* __restrict__ x, ushort_t* __restrict__ xb) {
    int idx = blockIdx.x * 256 + threadIdx.x;
    int n = idx >> 5;
    int c = idx & 31;
    float4 v = *(const float4*)(x + (size_t)n * 128 + c * 4);
    ushort4 o;
    o.x = f32_to_bf16(v.x); o.y = f32_to_bf16(v.y);
    o.z = f32_to_bf16(v.z); o.w = f32_to_bf16(v.w);
    *(ushort4*)(xb + (size_t)n * 128 + c * 4) = o;
}

// B1: [N=256][K=1024]: k<128 -> sum_r Wself1[r][k][n]; else Wneigh1[k/128-1][k%128][n]
__global__ void prep_B1cat_k(const float* __restrict__ Wself, const float* __restrict__ Wneigh,
                             const float* __restrict__ b, ushort_t* __restrict__ Bcat,
                             float* __restrict__ bs) {
    int idx = blockIdx.x * 256 + threadIdx.x;  // 262144 + 256
    if (idx < 262144) {
        int n = idx >> 10;
        int k = idx & 1023;
        float v;
        if (k < 128) {
            v = 0.f;
#pragma unroll
            for (int r = 0; r < 7; ++r) v += Wself[((size_t)r * 128 + k) * 256 + n];
        } else {
            int rel = (k >> 7) - 1;
            int k2 = k & 127;
            v = Wneigh[((size_t)rel * 128 + k2) * 256 + n];
        }
        Bcat[(size_t)n * 1024 + k] = f32_to_bf16(v);
    } else if (idx < 262400) {
        int i = idx - 262144;
        float s = 0.f;
#pragma unroll
        for (int r = 0; r < 7; ++r) s += b[r * 256 + i];
        bs[i] = s * (1.f / 7.f);
    }
}

// B2: [N=256][K=2048]: k<256 -> sum_r Wself2[r][k][n]; else Wneigh2[k/256-1][k%256][n]
__global__ void prep_B2cat_k(const float* __restrict__ Wself, const float* __restrict__ Wneigh,
                             const float* __restrict__ b, ushort_t* __restrict__ Bcat,
                             float* __restrict__ bs) {
    int idx = blockIdx.x * 256 + threadIdx.x;  // 524288 + 256
    if (idx < 524288) {
        int n = idx >> 11;
        int k = idx & 2047;
        float v;
        if (k < 256) {
            v = 0.f;
#pragma unroll
            for (int r = 0; r < 7; ++r) v += Wself[((size_t)r * 256 + k) * 256 + n];
        } else {
            int rel = (k >> 8) - 1;
            int k2 = k & 255;
            v = Wneigh[((size_t)rel * 256 + k2) * 256 + n];
        }
        Bcat[(size_t)n * 2048 + k] = f32_to_bf16(v);
    } else if (idx < 524544) {
        int i = idx - 524288;
        float s = 0.f;
#pragma unroll
        for (int r = 0; r < 7; ++r) s += b[r * 256 + i];
        bs[i] = s * (1.f / 7.f);
    }
}

__global__ void prep_cls_k(const float* __restrict__ Wc1, const float* __restrict__ bn_g,
                           const float* __restrict__ bn_b, const float* __restrict__ Wc2,
                           const float* __restrict__ bc2, ushort_t* __restrict__ Wc1T,
                           float* __restrict__ W2p, float* __restrict__ cp) {
    int idx = blockIdx.x * 256 + threadIdx.x;
    if (idx < 128 * 256) {
        int n = idx >> 8;
        int k = idx & 255;
        Wc1T[(size_t)n * 256 + k] = f32_to_bf16(Wc1[(size_t)k * 128 + n]);
    } else if (idx < 128 * 256 + 256) {
        int e = idx - 128 * 256;
        int d = e >> 1, j = e & 1;
        W2p[e] = bn_g[d] * rsqrtf(1.f + 1e-5f) * Wc2[d * 2 + j];
    } else if (idx < 128 * 256 + 256 + 2) {
        int j = idx - (128 * 256 + 256);
        float s = bc2[j];
        for (int d = 0; d < 128; ++d) s += bn_b[d] * Wc2[d * 2 + j];
        cp[j] = s;
    }
}

// ---------------- neighbor mean via CSR gather, merged relations -----------
// grid (sliceM/4, 7): blockIdx.y = relation. Writes slice-local rows at
// M0 + r*sliceM*D + (n-n0)*D. Clamp-masked 8-wide loop; readfirstlane'd
// start/cnt. NT-load csr stream + NT-store mean output (streaming data must
// not evict the gather table from L2/L3 -- R9 theory).
template <int V>
__global__ __launch_bounds__(256) void gather_mean_k(
    const ushort_t* __restrict__ T, const int* __restrict__ csr,
    const int* __restrict__ rowptr, const int* __restrict__ deg,
    ushort_t* __restrict__ M0, int n0, int sliceM) {
    int r = blockIdx.y;
    int n = n0 + blockIdx.x * 4 + (threadIdx.x >> 6);
    if (n >= NN) return;
    int lane = threadIdx.x & 63;
    ushort_t* Mout = M0 + (size_t)r * sliceM * (V * 128);
    int pair = r * NN + n;
    int start = __builtin_amdgcn_readfirstlane(rowptr[pair]);
    int cnt = __builtin_amdgcn_readfirstlane(deg[pair]);
    int cm1 = (cnt > 0) ? (cnt - 1) : 0;
    if (cnt <= 0) start = 0;             // clamped reads hit csr[0] (valid)
    const int* cp = csr + start;
    float inv = 1.f / (float)(cnt > 1 ? cnt : 1);
    if (V == 1) {
        const uint* Tu = (const uint*)T;
        float aLo[2] = {0.f, 0.f}, aHi[2] = {0.f, 0.f};
        for (int j = 0; j < cnt; j += 8) {
            int s[8];
            uint u[8];
#pragma unroll
            for (int q = 0; q < 8; ++q) {
                int e = j + q;
                s[q] = __builtin_nontemporal_load(cp + (e < cm1 ? e : cm1));
            }
#pragma unroll
            for (int q = 0; q < 8; ++q) u[q] = Tu[(size_t)s[q] * 64 + lane];
#pragma unroll
            for (int q = 0; q < 8; ++q) {
                uint m = (j + q < cnt) ? u[q] : 0u;
                aLo[q & 1] += bf16lo(m);
                aHi[q & 1] += bf16hi(m);
            }
        }
        uint lo = f32_to_bf16((aLo[0] + aLo[1]) * inv);
        uint hi = f32_to_bf16((aHi[0] + aHi[1]) * inv);
        __builtin_nontemporal_store(lo | (hi << 16),
                                    (uint*)(Mout + (size_t)(n - n0) * 128) + lane);
    } else {
        const uint2* Tu = (const uint2*)T;
        float aLo[2][2] = {{0.f, 0.f}, {0.f, 0.f}};
        float aHi[2][2] = {{0.f, 0.f}, {0.f, 0.f}};
        for (int j = 0; j < cnt; j += 8) {
            int s[8];
            uint2 u[8];
#pragma unroll
            for (int q = 0; q < 8; ++q) {
                int e = j + q;
                s[q] = __builtin_nontemporal_load(cp + (e < cm1 ? e : cm1));
            }
#pragma unroll
            for (int q = 0; q < 8; ++q) u[q] = Tu[(size_t)s[q] * 64 + lane];
#pragma unroll
            for (int q = 0; q < 8; ++q) {
                bool ok = (j + q < cnt);
                uint mx = ok ? u[q].x : 0u;
                uint my = ok ? u[q].y : 0u;
                aLo[0][q & 1] += bf16lo(mx);
                aHi[0][q & 1] += bf16hi(mx);
                aLo[1][q & 1] += bf16lo(my);
                aHi[1][q & 1] += bf16hi(my);
            }
        }
        uint lox = f32_to_bf16((aLo[0][0] + aLo[0][1]) * inv);
        uint hix = f32_to_bf16((aHi[0][0] + aHi[0][1]) * inv);
        uint loy = f32_to_bf16((aLo[1][0] + aLo[1][1]) * inv);
        uint hiy = f32_to_bf16((aHi[1][0] + aHi[1][1]) * inv);
        uintx2 o;
        o.x = lox | (hix << 16);
        o.y = loy | (hiy << 16);
        __builtin_nontemporal_store(o,
            (uintx2*)(Mout + (size_t)(n - n0) * 256) + lane);
    }
}

// ---------------- multi-segment bf16 MFMA GEMM (m97-style staging) ---------
// A = concat along K of: seg0 = A0[aoff + row][D] (self table, row-major),
// seg s>=1 = AM + (s-1)*Mseg*D (slice-local mean buffers, row-major D).
// Tile 128x128 (C9b-verified). Flat grid with XCD-paired column blocks.
// mode 2: Cbf16 = a*acc+bias    4: Cf32 = relu(a*acc+bias)
__global__ __launch_bounds__(256) void gemm_multi(
    const ushort_t* __restrict__ A0, const ushort_t* __restrict__ AM,
    int D, int lgD, int aoff, int Mseg, const ushort_t* __restrict__ BT,
    void* __restrict__ Cv, int M, int N, int K, float alpha,
    const float* __restrict__ bias, int mode) {
    __shared__ __align__(16) ushort_t lA[2 * 4096];  // 2 sub-panels of 128x32
    __shared__ __align__(16) ushort_t lB[2 * 4096];
    int t = threadIdx.x;
    int Mblk = (M + 127) >> 7;
    int p, colb;
    if (N > 128) {                       // 2 column blocks, XCD-paired
        int bid = blockIdx.x;
        int q = bid >> 4, r = bid & 15;
        p = q * 8 + (r & 7);
        colb = r >> 3;
        if (p >= Mblk) return;           // tail guard (block-uniform)
    } else {
        p = blockIdx.x;
        colb = 0;
    }
    int gr0 = p * 128;
    int gc0 = colb * 128;
    int w = t >> 6, lane = t & 63;
    int wr = w >> 1, wc = w & 1;
    int lm = lane & 15, quad = lane >> 4;
    int srow = lane >> 2;            // staging: row within 16-row group
    int schunk = (lane & 3) * 8;     // staging: 8-ushort chunk within 32
    const ushort_t* A0s = A0 + (size_t)aoff * D;
    size_t segstride = (size_t)Mseg * D;
    f32x4 acc[4][4];
#pragma unroll
    for (int i = 0; i < 4; ++i)
#pragma unroll
        for (int j = 0; j < 4; ++j) acc[i][j] = (f32x4){0.f, 0.f, 0.f, 0.f};

    for (int kk = 0; kk < K; kk += 64) {
        int seg = kk >> lgD;
        int kloc = kk & (D - 1);
        const ushort_t* Asrc = (seg == 0) ? A0s : (AM + (size_t)(seg - 1) * segstride);
        __syncthreads();
#pragma unroll
        for (int s = 0; s < 2; ++s) {
#pragma unroll
            for (int j = 0; j < 2; ++j) {
                int rb = (j * 4 + w) * 16;        // wave-uniform row base
                int row = rb + srow;
                int gr = gr0 + row;
                if (gr < M)
                    gload16(Asrc + (size_t)gr * D + kloc + s * 32 + schunk,
                            lA + s * 4096 + rb * 32);
                gload16(BT + (size_t)(gc0 + row) * K + kk + s * 32 + schunk,
                        lB + s * 4096 + rb * 32);
            }
        }
        __syncthreads();
#pragma unroll
        for (int s = 0; s < 2; ++s) {
            bf16x8 af[4], bfr[4];
#pragma unroll
            for (int f = 0; f < 4; ++f) {
                af[f] = *(const bf16x8*)(lA + s * 4096 + (wr * 64 + f * 16 + lm) * 32 + quad * 8);
                bfr[f] = *(const bf16x8*)(lB + s * 4096 + (wc * 64 + f * 16 + lm) * 32 + quad * 8);
            }
#pragma unroll
            for (int fr = 0; fr < 4; ++fr)
#pragma unroll
                for (int fc = 0; fc < 4; ++fc)
                    acc[fr][fc] = __builtin_amdgcn_mfma_f32_16x16x32_bf16(
                        af[fr], bfr[fc], acc[fr][fc], 0, 0, 0);
        }
    }
    float* Cf = (float*)Cv;
    ushort_t* Cb = (ushort_t*)Cv;
#pragma unroll
    for (int fr = 0; fr < 4; ++fr) {
#pragma unroll
        for (int fc = 0; fc < 4; ++fc) {
#pragma unroll
            for (int i = 0; i < 4; ++i) {
                int row = wr * 64 + fr * 16 + quad * 4 + i;
                int col = wc * 64 + fc * 16 + lm;
                int gr = gr0 + row;
                int gc = gc0 + col;
                if (gr < M) {
                    size_t o = (size_t)gr * N + gc;
                    float v = acc[fr][fc][i] * alpha;
                    v += bias ? bias[gc] : 0.f;
                    if (mode == 4) {
                        Cf[o] = fmaxf(v, 0.f);
                    } else {
                        Cb[o] = f32_to_bf16(v);
                    }
                }
            }
        }
    }
}

// ---------------- LayerNorm + ReLU, bf16 in -> bf16 out (row-major) --------
__global__ __launch_bounds__(256) void ln_relu_b_k(
    const ushort_t* __restrict__ h, const float* __restrict__ g,
    const float* __restrict__ b, ushort_t* __restrict__ out) {
    int n = blockIdx.x * 4 + (threadIdx.x >> 6);
    if (n >= NN) return;
    int lane = threadIdx.x & 63;
    uint2 u = ((const uint2*)(h + (size_t)n * 256))[lane];
    float v0 = bf16lo(u.x), v1 = bf16hi(u.x), v2 = bf16lo(u.y), v3 = bf16hi(u.y);
    float s = v0 + v1 + v2 + v3;
    float q = v0 * v0 + v1 * v1 + v2 * v2 + v3 * v3;
#pragma unroll
    for (int m = 1; m < 64; m <<= 1) {
        s += __shfl_xor(s, m);
        q += __shfl_xor(q, m);
    }
    float mean = s * (1.f / 256.f);
    float var = q * (1.f / 256.f) - mean * mean;
    float rs = rsqrtf(var + 1e-5f);
    float4 gv = *(const float4*)(g + lane * 4);
    float4 bv = *(const float4*)(b + lane * 4);
    float y0 = fmaxf((v0 - mean) * rs * gv.x + bv.x, 0.f);
    float y1 = fmaxf((v1 - mean) * rs * gv.y + bv.y, 0.f);
    float y2 = fmaxf((v2 - mean) * rs * gv.z + bv.z, 0.f);
    float y3 = fmaxf((v3 - mean) * rs * gv.w + bv.w, 0.f);
    uint2 o;
    o.x = (uint)f32_to_bf16(y0) | ((uint)f32_to_bf16(y1) << 16);
    o.y = (uint)f32_to_bf16(y2) | ((uint)f32_to_bf16(y3) << 16);
    *(uint2*)(out + (size_t)n * 256 + lane * 4) = o;
}

// ---------------- final 128 -> 2 with folded BN ----------------
__global__ __launch_bounds__(256) void final_k(const float* __restrict__ z1,
                                               const float* __restrict__ W2p,
                                               const float* __restrict__ cp,
                                               float* __restrict__ out) {
    int n = blockIdx.x * 4 + (threadIdx.x >> 6);
    if (n >= NN) return;
    int lane = threadIdx.x & 63;
    const float* zr = z1 + (size_t)n * 128;
    float z0 = zr[lane], z1v = zr[lane + 64];
    float a0 = z0 * W2p[lane * 2 + 0] + z1v * W2p[(lane + 64) * 2 + 0];
    float a1 = z0 * W2p[lane * 2 + 1] + z1v * W2p[(lane + 64) * 2 + 1];
#pragma unroll
    for (int m = 1; m < 64; m <<= 1) {
        a0 += __shfl_xor(a0, m);
        a1 += __shfl_xor(a1, m);
    }
    if (lane == 0) {
        out[(size_t)n * 2 + 0] = a0 + cp[0];
        out[(size_t)n * 2 + 1] = a1 + cp[1];
    }
}

// ---------------- workspace layout ------------------------------------------
// Common head (both paths):
constexpr size_t O_DEG   = 0;              // 2,800,000 -> pad 2,800,128
constexpr size_t O_ROW   = 2800128;        // 2,800,000 -> 5,600,256 (pad)
constexpr size_t O_BLK   = 5600256;        // pad 1024
constexpr size_t O_CSR   = 5601280;        // 44,800,000 -> 50,401,280
constexpr size_t O_B1C   = 50401280;       // 524,288
constexpr size_t O_B2C   = 50925568;       // 1,048,576
constexpr size_t O_WC1T  = 51974144;       // 65,536
constexpr size_t O_W2P   = 52039680;       // 1024
constexpr size_t O_CP    = 52040704;       // 256
constexpr size_t O_B1S   = 52040960;       // 1024
constexpr size_t O_B2S   = 52041984;       // 1024
constexpr size_t O_XB    = 52043008;       // xb bf16 row-major 25,600,000
// CSR-build scratch (dead before convert_x). bcnt FIRST, then the bucket
// buffer sized 896*BCAP*4 = 51,380,224 B.
constexpr size_t O_BCNT  = 52043008;       // 4096 -> 52,047,104
constexpr size_t O_BPK   = 52047104;       // 51,380,224 -> 103,427,328
// FULL path (L1 full means, L2 half means):
constexpr size_t OF_MEAN1 = 77643008;      // 7x100000x128 bf16 = 179,200,000 -> 256,843,008
constexpr size_t OF_HACC1 = 256843008;     // 51,200,000 -> 308,043,008
constexpr size_t OF_H1B   = 52043008;      // 51,200,000 (xb + mean1 head dead) -> 103,243,008
constexpr size_t OF_MEAN2 = 103243008;     // 7x50000x256 bf16 = 179,200,000 -> 282,443,008
constexpr size_t OF_HACC2 = 282443008;     // 51,200,000 -> 333,643,008
constexpr size_t OF_H2B   = 52043008;      // (h1b dead after L2 GEMMs)
constexpr size_t OF_Z1    = 103243008;     // f32 51,200,000 (mean2 dead)
constexpr size_t WS_FULL  = 333643008;
// FALLBACK path (= C8: L1 halves, L2 quarters):
constexpr size_t OQ_MEAN1 = 77643008;      // 7x50000x128 bf16 = 89,600,000
constexpr size_t OQ_HACC1 = 167243008;     // 51,200,000 -> 218,443,008
constexpr size_t OQ_H1B   = 52043008;
constexpr size_t OQ_MEAN2 = 103243008;     // 7x25000x256 bf16 = 89,600,000
constexpr size_t OQ_HACC2 = 192843008;     // 51,200,000 -> 244,043,008
constexpr size_t OQ_H2B   = 52043008;
constexpr size_t OQ_Z1    = 103243008;
constexpr size_t WS_QUART = 244043008;

extern "C" void kernel_launch(void* const* d_in, const int* in_sizes, int n_in,
                              void* d_out, int out_size, void* d_ws, size_t ws_size,
                              hipStream_t stream) {
    (void)in_sizes; (void)n_in;
    const float* features = (const float*)d_in[0];
    const int* edges = (const int*)d_in[1];
    const float* Wself1 = (const float*)d_in[2];
    const float* Wneigh1 = (const float*)d_in[3];
    const float* b1 = (const float*)d_in[4];
    const float* Wself2 = (const float*)d_in[5];
    const float* Wneigh2 = (const float*)d_in[6];
    const float* b2 = (const float*)d_in[7];
    const float* ln_g = (const float*)d_in[8];
    const float* ln_b = (const float*)d_in[9];
    const float* Wc1 = (const float*)d_in[10];
    const float* bc1 = (const float*)d_in[11];
    const float* bn_g = (const float*)d_in[12];
    const float* bn_b = (const float*)d_in[13];
    const float* Wc2 = (const float*)d_in[14];
    const float* bc2 = (const float*)d_in[15];
    float* out = (float*)d_out;
    char* ws = (char*)d_ws;

    if (ws_size < WS_QUART) {
        hipMemsetAsync(d_out, 0, (size_t)out_size * 4, stream);
        return;
    }
    bool full = (ws_size >= WS_FULL);

    int* deg = (int*)(ws + O_DEG);
    int* rowptr = (int*)(ws + O_ROW);
    int* blk = (int*)(ws + O_BLK);
    int* csr = (int*)(ws + O_CSR);
    ushort_t* B1cat = (ushort_t*)(ws + O_B1C);
    ushort_t* B2cat = (ushort_t*)(ws + O_B2C);
    ushort_t* Wc1T = (ushort_t*)(ws + O_WC1T);
    float* W2p = (float*)(ws + O_W2P);
    float* cp = (float*)(ws + O_CP);
    float* b1s = (float*)(ws + O_B1S);
    float* b2s = (float*)(ws + O_B2S);
    ushort_t* xb = (ushort_t*)(ws + O_XB);
    int* bcnt = (int*)(ws + O_BCNT);
    uint* bpack = (uint*)(ws + O_BPK);

    ushort_t* mean1 = (ushort_t*)(ws + (full ? OF_MEAN1 : OQ_MEAN1));
    ushort_t* hacc1 = (ushort_t*)(ws + (full ? OF_HACC1 : OQ_HACC1));
    ushort_t* h1b   = (ushort_t*)(ws + (full ? OF_H1B : OQ_H1B));
    ushort_t* mean2 = (ushort_t*)(ws + (full ? OF_MEAN2 : OQ_MEAN2));
    ushort_t* hacc2 = (ushort_t*)(ws + (full ? OF_HACC2 : OQ_HACC2));
    ushort_t* h2b   = (ushort_t*)(ws + (full ? OF_H2B : OQ_H2B));
    float* z1       = (float*)(ws + (full ? OF_Z1 : OQ_Z1));

    hipMemsetAsync(bcnt, 0, 4096, stream);
    hipMemsetAsync(deg, 0, (size_t)NREL * NN * 4, stream);

    // ---- CSR build (deg fused into binpass; scratch dead before convert_x)
    binpass_k<<<dim3(391, 7, 1), 256, 0, stream>>>(edges, bcnt, bpack, deg);
    scan1_k<<<171, 256, 0, stream>>>(deg, rowptr, blk, NREL * NN);
    scan2_k<<<1, 64, 0, stream>>>(blk, 171);
    scan3_k<<<171, 256, 0, stream>>>(rowptr, blk, NREL * NN);
    bucket_sort_k<<<896, 1024, 0, stream>>>(bpack, bcnt, rowptr, csr);

    // ---- weight prep + x -> bf16 ----
    convert_x_k<<<12500, 256, 0, stream>>>(features, xb);
    prep_B1cat_k<<<1025, 256, 0, stream>>>(Wself1, Wneigh1, b1, B1cat, b1s);
    prep_B2cat_k<<<2050, 256, 0, stream>>>(Wself2, Wneigh2, b2, B2cat, b2s);
    prep_cls_k<<<130, 256, 0, stream>>>(Wc1, bn_g, bn_b, Wc2, bc2, Wc1T, W2p, cp);

    if (full) {
        // ---- layer 1: full means; GEMM grid 16*ceil(782/8)=1568 flat ----
        gather_mean_k<1><<<dim3(25000, 7, 1), 256, 0, stream>>>(
            xb, csr, rowptr, deg, mean1, 0, 100000);
        gemm_multi<<<dim3(1568, 1, 1), 256, 0, stream>>>(
            xb, mean1, 128, 7, 0, 100000, B1cat,
            hacc1, 100000, 256, 1024, 1.f / 7.f, b1s, 2);
        ln_relu_b_k<<<25000, 256, 0, stream>>>(hacc1, ln_g, ln_b, h1b);

        // ---- layer 2: 2 halves; GEMM grid 16*ceil(391/8)=784 flat ----
        for (int h = 0; h < 2; ++h) {
            int n0 = h * 50000;
            gather_mean_k<2><<<dim3(12500, 7, 1), 256, 0, stream>>>(
                h1b, csr, rowptr, deg, mean2, n0, 50000);
            gemm_multi<<<dim3(784, 1, 1), 256, 0, stream>>>(
                h1b, mean2, 256, 8, n0, 50000, B2cat,
                hacc2 + (size_t)n0 * 256, 50000, 256, 2048, 1.f / 7.f, b2s, 2);
        }
        ln_relu_b_k<<<25000, 256, 0, stream>>>(hacc2, ln_g + 256, ln_b + 256, h2b);
    } else {
        // ---- fallback (C8 slicing, merged-relation gathers) ----
        for (int h = 0; h < 2; ++h) {
            int n0 = h * 50000;
            gather_mean_k<1><<<dim3(12500, 7, 1), 256, 0, stream>>>(
                xb, csr, rowptr, deg, mean1, n0, 50000);
            gemm_multi<<<dim3(784, 1, 1), 256, 0, stream>>>(
                xb, mean1, 128, 7, n0, 50000, B1cat,
                hacc1 + (size_t)n0 * 256, 50000, 256, 1024, 1.f / 7.f, b1s, 2);
        }
        ln_relu_b_k<<<25000, 256, 0, stream>>>(hacc1, ln_g, ln_b, h1b);

        for (int q = 0; q < 4; ++q) {
            int n0 = q * 25000;
            gather_mean_k<2><<<dim3(6250, 7, 1), 256, 0, stream>>>(
                h1b, csr, rowptr, deg, mean2, n0, 25000);
            gemm_multi<<<dim3(400, 1, 1), 256, 0, stream>>>(
                h1b, mean2, 256, 8, n0, 25000, B2cat,
                hacc2 + (size_t)n0 * 256, 25000, 256, 2048, 1.f / 7.f, b2s, 2);
        }
        ln_relu_b_k<<<25000, 256, 0, stream>>>(hacc2, ln_g + 256, ln_b + 256, h2b);
    }

    // ---- classifier (N=128: single column block, p = blockIdx.x) ----
    gemm_multi<<<dim3(782, 1, 1), 256, 0, stream>>>(
        h2b, nullptr, 256, 8, 0, 0, Wc1T, z1, NN, 128, 256, 1.f, bc1, 4);
    final_k<<<25000, 256, 0, stream>>>(z1, W2p, cp, out);
}

// Round 10
// 1861.068 us; speedup vs baseline: 1.2202x; 1.2202x over previous
//
#include <hip/hip_runtime.h>
#include <hip/hip_bf16.h>
#include <cstdint>

// ---------------------------------------------------------------------------
// HeteroGNN: 2-layer hetero-SAGE (7 rel, 1.6M edges) + classifier, 100k nodes.
// Design C13 = C11 restored (R9 post-mortem: both R9 changes regressed).
//  * [R9 falsified] deg fused via global atomicAdd: 11.2M random
//    device-scope atomics -> 399 MB write traffic, binpass 85->452 us.
//    deg_bucket_k (LDS histogram) restored.
//  * [R9 falsified] NT-store/NT-load on gather streams: no FETCH drop --
//    gather re-fetch is capacity-miss of a random-512B working set over
//    32 MB L2, not write-stream eviction. Plain loads/stores restored.
//  * [R8 verified: 1862.4 us] XCD-paired GEMM column blocks (+13 us).
//  * [R6 verified] merged-K GEMM per layer (C written once, f32 reg acc),
//    adaptive slicing by grant, consolidated gathers (blockIdx.y = rel),
//    packed binpass records, clamp-masked 8-wide gather loop.
//  * Gathers: 3 big dispatches @ ~378 us, 49% HBM, 3.9 TB/s effective on
//    random 512-B granules == measured pattern-roofline (R6/R7/R8 tripled).
// ---------------------------------------------------------------------------

#define NN 100000
#define NREL 7
#define NE 1600000
#define NB 128           // buckets per relation
#define BCAP 14336       // slots per bucket (mean 12500)
#define BNODES 782       // ceil(100000/128)

using uint = unsigned int;
using ushort_t = unsigned short;
using bf16x8 = __attribute__((ext_vector_type(8))) __bf16;
using f32x4 = __attribute__((ext_vector_type(4))) float;

__device__ __forceinline__ ushort_t f32_to_bf16(float f) {
    uint u = __float_as_uint(f);
    u += 0x7fffu + ((u >> 16) & 1u);
    return (ushort_t)(u >> 16);
}
__device__ __forceinline__ float bf16lo(uint u) { return __uint_as_float(u << 16); }
__device__ __forceinline__ float bf16hi(uint u) { return __uint_as_float(u & 0xffff0000u); }

// async global->LDS, 16B per lane; LDS dest = wave-uniform base + lane*16
__device__ __forceinline__ void gload16(const ushort_t* g, ushort_t* l) {
    __builtin_amdgcn_global_load_lds(
        (const __attribute__((address_space(1))) uint*)g,
        (__attribute__((address_space(3))) uint*)l, 16, 0, 0);
}

// ---------------- CSR build: pass 1 — LDS bucket binning -------------------
// Packed record: (src << 10) | dstlocal   (src < 2^17, dstlocal < 782 < 2^10)
__global__ __launch_bounds__(256) void binpass_k(const int* __restrict__ edges,
                                                 int* __restrict__ bcnt,
                                                 uint* __restrict__ bpack) {
    __shared__ int cnt[NB];
    __shared__ int lofs[NB];
    __shared__ int gbase[NB];
    __shared__ int wtot[2];
    __shared__ int stotal;
    __shared__ uint stage[4096];
    __shared__ unsigned char bb[4096];
    int r = blockIdx.y;
    int t = threadIdx.x;
    if (t < NB) cnt[t] = 0;
    __syncthreads();
    int e0 = blockIdx.x * 4096;
    uint mypack[16];
    int myrb[16];
#pragma unroll
    for (int i = 0; i < 16; ++i) {
        int e = e0 + i * 256 + t;
        if (e < NE) {
            int s = edges[(size_t)(2 * r) * NE + e];
            int d = edges[(size_t)(2 * r + 1) * NE + e];
            int b = d / BNODES;
            int dl = d - b * BNODES;
            int rank = atomicAdd(&cnt[b], 1);
            myrb[i] = (rank << 7) | b;
            mypack[i] = ((uint)s << 10) | (uint)dl;
        } else {
            myrb[i] = -1;
        }
    }
    __syncthreads();
    {
        int c = (t < NB) ? cnt[t] : 0;
        int lane = t & 63, wv = t >> 6;
        int x = c;
#pragma unroll
        for (int off = 1; off < 64; off <<= 1) {
            int y = __shfl_up(x, off);
            if (lane >= off) x += y;
        }
        if (t < NB && lane == 63) wtot[wv] = x;
        __syncthreads();
        if (t < NB) {
            int excl = x - c + (wv ? wtot[0] : 0);
            lofs[t] = excl;
            gbase[t] = atomicAdd(&bcnt[r * NB + t], c);
            if (t == NB - 1) stotal = excl + c;
        }
    }
    __syncthreads();
#pragma unroll
    for (int i = 0; i < 16; ++i) {
        if (myrb[i] >= 0) {
            int b = myrb[i] & 127;
            int p = lofs[b] + (myrb[i] >> 7);
            stage[p] = mypack[i];
            bb[p] = (unsigned char)b;
        }
    }
    __syncthreads();
    int total = stotal;
    for (int p = t; p < total; p += 256) {
        int b = bb[p];
        uint pr = stage[p];
        int gpos = gbase[b] + (p - lofs[b]);
        if (gpos < BCAP) {
            bpack[((size_t)r * NB + b) * BCAP + gpos] = pr;
        }
    }
}

// ---------------- CSR build: per-bucket LDS degree histogram ---------------
__global__ __launch_bounds__(1024) void deg_bucket_k(const uint* __restrict__ bpack,
                                                     const int* __restrict__ bcnt,
                                                     int* __restrict__ deg) {
    __shared__ int hist[BNODES];
    int rb = blockIdx.x;
    int r = rb >> 7, b = rb & 127;
    int node0 = b * BNODES;
    int nnodes = NN - node0 < BNODES ? NN - node0 : BNODES;
    int t = threadIdx.x;
    for (int i = t; i < nnodes; i += 1024) hist[i] = 0;
    __syncthreads();
    int cb = bcnt[rb];
    if (cb > BCAP) cb = BCAP;
    const uint* src = bpack + (size_t)rb * BCAP;
    for (int i = t; i < cb; i += 1024) {
        atomicAdd(&hist[src[i] & 1023u], 1);
    }
    __syncthreads();
    for (int i = t; i < nnodes; i += 1024) deg[r * NN + node0 + i] = hist[i];
}

// ---------------- CSR build: scan (deg -> rowptr) ----------------
__global__ void scan1_k(const int* __restrict__ deg, int* __restrict__ rowptr,
                        int* __restrict__ blk, int total) {
    __shared__ int wsum[4];
    int t = threadIdx.x;
    int base = blockIdx.x * 4096 + t * 16;
    int vals[16];
    int s = 0;
#pragma unroll
    for (int i = 0; i < 16; ++i) {
        int g = base + i;
        int v = (g < total) ? deg[g] : 0;
        vals[i] = s;
        s += v;
    }
    int lane = t & 63, w = t >> 6;
    int x = s;
    for (int off = 1; off < 64; off <<= 1) {
        int y = __shfl_up(x, off);
        if (lane >= off) x += y;
    }
    if (lane == 63) wsum[w] = x;
    __syncthreads();
    if (t == 0) {
        int a = 0;
#pragma unroll
        for (int k = 0; k < 4; ++k) { int b = wsum[k]; wsum[k] = a; a += b; }
        blk[blockIdx.x] = a;
    }
    __syncthreads();
    int excl = x - s + wsum[w];
#pragma unroll
    for (int i = 0; i < 16; ++i) {
        int g = base + i;
        if (g < total) rowptr[g] = excl + vals[i];
    }
}

__global__ void scan2_k(int* blk, int nb) {
    if (threadIdx.x == 0 && blockIdx.x == 0) {
        int a = 0;
        for (int i = 0; i < nb; ++i) { int b = blk[i]; blk[i] = a; a += b; }
    }
}

__global__ void scan3_k(int* __restrict__ rowptr, const int* __restrict__ blk, int total) {
    int t = threadIdx.x;
    int add = blk[blockIdx.x];
    int base = blockIdx.x * 4096 + t * 16;
#pragma unroll
    for (int i = 0; i < 16; ++i) {
        int g = base + i;
        if (g < total) rowptr[g] += add;
    }
}

// ---------------- CSR build: per-bucket LDS counting sort ------------------
__global__ __launch_bounds__(1024) void bucket_sort_k(const uint* __restrict__ bpack,
                                                      const int* __restrict__ bcnt,
                                                      const int* __restrict__ rowptr,
                                                      int* __restrict__ csr) {
    __shared__ int stage[BCAP];
    __shared__ int lcur[BNODES];
    int rb = blockIdx.x;
    int r = rb >> 7, b = rb & 127;
    int node0 = b * BNODES;
    int nnodes = NN - node0 < BNODES ? NN - node0 : BNODES;
    int t = threadIdx.x;
    int rowbase = rowptr[r * NN + node0];
    int endIdx = r * NN + node0 + nnodes;
    int rowend = (endIdx < NREL * NN) ? rowptr[endIdx] : (NREL * NE);
    int truen = rowend - rowbase;
    int nent = truen < BCAP ? truen : BCAP;
    for (int i = t; i < nent; i += 1024) stage[i] = 0;
    for (int i = t; i < nnodes; i += 1024) lcur[i] = 0;
    __syncthreads();
    int cb = bcnt[rb];
    if (cb > BCAP) cb = BCAP;
    for (int i = t; i < cb; i += 1024) {
        uint v = bpack[(size_t)rb * BCAP + i];
        int nl = (int)(v & 1023u);
        int sv = (int)(v >> 10);
        int pos = rowptr[r * NN + node0 + nl] - rowbase + atomicAdd(&lcur[nl], 1);
        if (pos < BCAP) stage[pos] = sv;
    }
    __syncthreads();
    for (int i = t; i < nent; i += 1024) csr[rowbase + i] = stage[i];
    for (int i = nent + t; i < truen; i += 1024) csr[rowbase + i] = 0;
}

// ---------------- conversions / weight prep ----------------
__global__ void convert_x_k(const float* __restrict__ x, ushort_t* __restrict__ xb) {
    int idx = blockIdx.x * 256 + threadIdx.x;
    int n = idx >> 5;
    int c = idx & 31;
    float4 v = *(const float4*)(x + (size_t)n * 128 + c * 4);
    ushort4 o;
    o.x = f32_to_bf16(v.x); o.y = f32_to_bf16(v.y);
    o.z = f32_to_bf16(v.z); o.w = f32_to_bf16(v.w);
    *(ushort4*)(xb + (size_t)n * 128 + c * 4) = o;
}

// B1: [N=256][K=1024]: k<128 -> sum_r Wself1[r][k][n]; else Wneigh1[k/128-1][k%128][n]
__global__ void prep_B1cat_k(const float* __restrict__ Wself, const float* __restrict__ Wneigh,
                             const float* __restrict__ b, ushort_t* __restrict__ Bcat,
                             float* __restrict__ bs) {
    int idx = blockIdx.x * 256 + threadIdx.x;  // 262144 + 256
    if (idx < 262144) {
        int n = idx >> 10;
        int k = idx & 1023;
        float v;
        if (k < 128) {
            v = 0.f;
#pragma unroll
            for (int r = 0; r < 7; ++r) v += Wself[((size_t)r * 128 + k) * 256 + n];
        } else {
            int rel = (k >> 7) - 1;
            int k2 = k & 127;
            v = Wneigh[((size_t)rel * 128 + k2) * 256 + n];
        }
        Bcat[(size_t)n * 1024 + k] = f32_to_bf16(v);
    } else if (idx < 262400) {
        int i = idx - 262144;
        float s = 0.f;
#pragma unroll
        for (int r = 0; r < 7; ++r) s += b[r * 256 + i];
        bs[i] = s * (1.f / 7.f);
    }
}

// B2: [N=256][K=2048]: k<256 -> sum_r Wself2[r][k][n]; else Wneigh2[k/256-1][k%256][n]
__global__ void prep_B2cat_k(const float* __restrict__ Wself, const float* __restrict__ Wneigh,
                             const float* __restrict__ b, ushort_t* __restrict__ Bcat,
                             float* __restrict__ bs) {
    int idx = blockIdx.x * 256 + threadIdx.x;  // 524288 + 256
    if (idx < 524288) {
        int n = idx >> 11;
        int k = idx & 2047;
        float v;
        if (k < 256) {
            v = 0.f;
#pragma unroll
            for (int r = 0; r < 7; ++r) v += Wself[((size_t)r * 256 + k) * 256 + n];
        } else {
            int rel = (k >> 8) - 1;
            int k2 = k & 255;
            v = Wneigh[((size_t)rel * 256 + k2) * 256 + n];
        }
        Bcat[(size_t)n * 2048 + k] = f32_to_bf16(v);
    } else if (idx < 524544) {
        int i = idx - 524288;
        float s = 0.f;
#pragma unroll
        for (int r = 0; r < 7; ++r) s += b[r * 256 + i];
        bs[i] = s * (1.f / 7.f);
    }
}

__global__ void prep_cls_k(const float* __restrict__ Wc1, const float* __restrict__ bn_g,
                           const float* __restrict__ bn_b, const float* __restrict__ Wc2,
                           const float* __restrict__ bc2, ushort_t* __restrict__ Wc1T,
                           float* __restrict__ W2p, float* __restrict__ cp) {
    int idx = blockIdx.x * 256 + threadIdx.x;
    if (idx < 128 * 256) {
        int n = idx >> 8;
        int k = idx & 255;
        Wc1T[(size_t)n * 256 + k] = f32_to_bf16(Wc1[(size_t)k * 128 + n]);
    } else if (idx < 128 * 256 + 256) {
        int e = idx - 128 * 256;
        int d = e >> 1, j = e & 1;
        W2p[e] = bn_g[d] * rsqrtf(1.f + 1e-5f) * Wc2[d * 2 + j];
    } else if (idx < 128 * 256 + 256 + 2) {
        int j = idx - (128 * 256 + 256);
        float s = bc2[j];
        for (int d = 0; d < 128; ++d) s += bn_b[d] * Wc2[d * 2 + j];
        cp[j] = s;
    }
}

// ---------------- neighbor mean via CSR gather, merged relations -----------
// grid (sliceM/4, 7): blockIdx.y = relation. Writes slice-local rows at
// M0 + r*sliceM*D + (n-n0)*D. Clamp-masked 8-wide loop (no scalar tail);
// start/cnt readfirstlane'd -> uniform loop + scalar csr loads.
template <int V>
__global__ __launch_bounds__(256) void gather_mean_k(
    const ushort_t* __restrict__ T, const int* __restrict__ csr,
    const int* __restrict__ rowptr, const int* __restrict__ deg,
    ushort_t* __restrict__ M0, int n0, int sliceM) {
    int r = blockIdx.y;
    int n = n0 + blockIdx.x * 4 + (threadIdx.x >> 6);
    if (n >= NN) return;
    int lane = threadIdx.x & 63;
    ushort_t* Mout = M0 + (size_t)r * sliceM * (V * 128);
    int pair = r * NN + n;
    int start = __builtin_amdgcn_readfirstlane(rowptr[pair]);
    int cnt = __builtin_amdgcn_readfirstlane(deg[pair]);
    int cm1 = (cnt > 0) ? (cnt - 1) : 0;
    if (cnt <= 0) start = 0;             // clamped reads hit csr[0] (valid)
    const int* cp = csr + start;
    float inv = 1.f / (float)(cnt > 1 ? cnt : 1);
    if (V == 1) {
        const uint* Tu = (const uint*)T;
        float aLo[2] = {0.f, 0.f}, aHi[2] = {0.f, 0.f};
        for (int j = 0; j < cnt; j += 8) {
            int s[8];
            uint u[8];
#pragma unroll
            for (int q = 0; q < 8; ++q) {
                int e = j + q;
                s[q] = cp[e < cm1 ? e : cm1];
            }
#pragma unroll
            for (int q = 0; q < 8; ++q) u[q] = Tu[(size_t)s[q] * 64 + lane];
#pragma unroll
            for (int q = 0; q < 8; ++q) {
                uint m = (j + q < cnt) ? u[q] : 0u;
                aLo[q & 1] += bf16lo(m);
                aHi[q & 1] += bf16hi(m);
            }
        }
        uint lo = f32_to_bf16((aLo[0] + aLo[1]) * inv);
        uint hi = f32_to_bf16((aHi[0] + aHi[1]) * inv);
        ((uint*)(Mout + (size_t)(n - n0) * 128))[lane] = lo | (hi << 16);
    } else {
        const uint2* Tu = (const uint2*)T;
        float aLo[2][2] = {{0.f, 0.f}, {0.f, 0.f}};
        float aHi[2][2] = {{0.f, 0.f}, {0.f, 0.f}};
        for (int j = 0; j < cnt; j += 8) {
            int s[8];
            uint2 u[8];
#pragma unroll
            for (int q = 0; q < 8; ++q) {
                int e = j + q;
                s[q] = cp[e < cm1 ? e : cm1];
            }
#pragma unroll
            for (int q = 0; q < 8; ++q) u[q] = Tu[(size_t)s[q] * 64 + lane];
#pragma unroll
            for (int q = 0; q < 8; ++q) {
                bool ok = (j + q < cnt);
                uint mx = ok ? u[q].x : 0u;
                uint my = ok ? u[q].y : 0u;
                aLo[0][q & 1] += bf16lo(mx);
                aHi[0][q & 1] += bf16hi(mx);
                aLo[1][q & 1] += bf16lo(my);
                aHi[1][q & 1] += bf16hi(my);
            }
        }
        uint lox = f32_to_bf16((aLo[0][0] + aLo[0][1]) * inv);
        uint hix = f32_to_bf16((aHi[0][0] + aHi[0][1]) * inv);
        uint loy = f32_to_bf16((aLo[1][0] + aLo[1][1]) * inv);
        uint hiy = f32_to_bf16((aHi[1][0] + aHi[1][1]) * inv);
        ((uint2*)(Mout + (size_t)(n - n0) * 256))[lane] =
            make_uint2(lox | (hix << 16), loy | (hiy << 16));
    }
}

// ---------------- multi-segment bf16 MFMA GEMM (m97-style staging) ---------
// A = concat along K of: seg0 = A0[aoff + row][D] (self table, row-major),
// seg s>=1 = AM + (s-1)*Mseg*D (slice-local mean buffers, row-major D).
// Tile 128x128 (C9b-verified). Flat grid with XCD-paired column blocks:
// for N=256, p = q*8+(r&7), col = r>>3 (q=bid>>4, r=bid&15) -> both column
// blocks of an A panel land on the same XCD -> second A read is an L2 hit.
// mode 2: Cbf16 = a*acc+bias    4: Cf32 = relu(a*acc+bias)
__global__ __launch_bounds__(256) void gemm_multi(
    const ushort_t* __restrict__ A0, const ushort_t* __restrict__ AM,
    int D, int lgD, int aoff, int Mseg, const ushort_t* __restrict__ BT,
    void* __restrict__ Cv, int M, int N, int K, float alpha,
    const float* __restrict__ bias, int mode) {
    __shared__ __align__(16) ushort_t lA[2 * 4096];  // 2 sub-panels of 128x32
    __shared__ __align__(16) ushort_t lB[2 * 4096];
    int t = threadIdx.x;
    int Mblk = (M + 127) >> 7;
    int p, colb;
    if (N > 128) {                       // 2 column blocks, XCD-paired
        int bid = blockIdx.x;
        int q = bid >> 4, r = bid & 15;
        p = q * 8 + (r & 7);
        colb = r >> 3;
        if (p >= Mblk) return;           // tail guard (block-uniform)
    } else {
        p = blockIdx.x;
        colb = 0;
    }
    int gr0 = p * 128;
    int gc0 = colb * 128;
    int w = t >> 6, lane = t & 63;
    int wr = w >> 1, wc = w & 1;
    int lm = lane & 15, quad = lane >> 4;
    int srow = lane >> 2;            // staging: row within 16-row group
    int schunk = (lane & 3) * 8;     // staging: 8-ushort chunk within 32
    const ushort_t* A0s = A0 + (size_t)aoff * D;
    size_t segstride = (size_t)Mseg * D;
    f32x4 acc[4][4];
#pragma unroll
    for (int i = 0; i < 4; ++i)
#pragma unroll
        for (int j = 0; j < 4; ++j) acc[i][j] = (f32x4){0.f, 0.f, 0.f, 0.f};

    for (int kk = 0; kk < K; kk += 64) {
        int seg = kk >> lgD;
        int kloc = kk & (D - 1);
        const ushort_t* Asrc = (seg == 0) ? A0s : (AM + (size_t)(seg - 1) * segstride);
        __syncthreads();
#pragma unroll
        for (int s = 0; s < 2; ++s) {
#pragma unroll
            for (int j = 0; j < 2; ++j) {
                int rb = (j * 4 + w) * 16;        // wave-uniform row base
                int row = rb + srow;
                int gr = gr0 + row;
                if (gr < M)
                    gload16(Asrc + (size_t)gr * D + kloc + s * 32 + schunk,
                            lA + s * 4096 + rb * 32);
                gload16(BT + (size_t)(gc0 + row) * K + kk + s * 32 + schunk,
                        lB + s * 4096 + rb * 32);
            }
        }
        __syncthreads();
#pragma unroll
        for (int s = 0; s < 2; ++s) {
            bf16x8 af[4], bfr[4];
#pragma unroll
            for (int f = 0; f < 4; ++f) {
                af[f] = *(const bf16x8*)(lA + s * 4096 + (wr * 64 + f * 16 + lm) * 32 + quad * 8);
                bfr[f] = *(const bf16x8*)(lB + s * 4096 + (wc * 64 + f * 16 + lm) * 32 + quad * 8);
            }
#pragma unroll
            for (int fr = 0; fr < 4; ++fr)
#pragma unroll
                for (int fc = 0; fc < 4; ++fc)
                    acc[fr][fc] = __builtin_amdgcn_mfma_f32_16x16x32_bf16(
                        af[fr], bfr[fc], acc[fr][fc], 0, 0, 0);
        }
    }
    float* Cf = (float*)Cv;
    ushort_t* Cb = (ushort_t*)Cv;
#pragma unroll
    for (int fr = 0; fr < 4; ++fr) {
#pragma unroll
        for (int fc = 0; fc < 4; ++fc) {
#pragma unroll
            for (int i = 0; i < 4; ++i) {
                int row = wr * 64 + fr * 16 + quad * 4 + i;
                int col = wc * 64 + fc * 16 + lm;
                int gr = gr0 + row;
                int gc = gc0 + col;
                if (gr < M) {
                    size_t o = (size_t)gr * N + gc;
                    float v = acc[fr][fc][i] * alpha;
                    v += bias ? bias[gc] : 0.f;
                    if (mode == 4) {
                        Cf[o] = fmaxf(v, 0.f);
                    } else {
                        Cb[o] = f32_to_bf16(v);
                    }
                }
            }
        }
    }
}

// ---------------- LayerNorm + ReLU, bf16 in -> bf16 out (row-major) --------
__global__ __launch_bounds__(256) void ln_relu_b_k(
    const ushort_t* __restrict__ h, const float* __restrict__ g,
    const float* __restrict__ b, ushort_t* __restrict__ out) {
    int n = blockIdx.x * 4 + (threadIdx.x >> 6);
    if (n >= NN) return;
    int lane = threadIdx.x & 63;
    uint2 u = ((const uint2*)(h + (size_t)n * 256))[lane];
    float v0 = bf16lo(u.x), v1 = bf16hi(u.x), v2 = bf16lo(u.y), v3 = bf16hi(u.y);
    float s = v0 + v1 + v2 + v3;
    float q = v0 * v0 + v1 * v1 + v2 * v2 + v3 * v3;
#pragma unroll
    for (int m = 1; m < 64; m <<= 1) {
        s += __shfl_xor(s, m);
        q += __shfl_xor(q, m);
    }
    float mean = s * (1.f / 256.f);
    float var = q * (1.f / 256.f) - mean * mean;
    float rs = rsqrtf(var + 1e-5f);
    float4 gv = *(const float4*)(g + lane * 4);
    float4 bv = *(const float4*)(b + lane * 4);
    float y0 = fmaxf((v0 - mean) * rs * gv.x + bv.x, 0.f);
    float y1 = fmaxf((v1 - mean) * rs * gv.y + bv.y, 0.f);
    float y2 = fmaxf((v2 - mean) * rs * gv.z + bv.z, 0.f);
    float y3 = fmaxf((v3 - mean) * rs * gv.w + bv.w, 0.f);
    uint2 o;
    o.x = (uint)f32_to_bf16(y0) | ((uint)f32_to_bf16(y1) << 16);
    o.y = (uint)f32_to_bf16(y2) | ((uint)f32_to_bf16(y3) << 16);
    *(uint2*)(out + (size_t)n * 256 + lane * 4) = o;
}

// ---------------- final 128 -> 2 with folded BN ----------------
__global__ __launch_bounds__(256) void final_k(const float* __restrict__ z1,
                                               const float* __restrict__ W2p,
                                               const float* __restrict__ cp,
                                               float* __restrict__ out) {
    int n = blockIdx.x * 4 + (threadIdx.x >> 6);
    if (n >= NN) return;
    int lane = threadIdx.x & 63;
    const float* zr = z1 + (size_t)n * 128;
    float z0 = zr[lane], z1v = zr[lane + 64];
    float a0 = z0 * W2p[lane * 2 + 0] + z1v * W2p[(lane + 64) * 2 + 0];
    float a1 = z0 * W2p[lane * 2 + 1] + z1v * W2p[(lane + 64) * 2 + 1];
#pragma unroll
    for (int m = 1; m < 64; m <<= 1) {
        a0 += __shfl_xor(a0, m);
        a1 += __shfl_xor(a1, m);
    }
    if (lane == 0) {
        out[(size_t)n * 2 + 0] = a0 + cp[0];
        out[(size_t)n * 2 + 1] = a1 + cp[1];
    }
}

// ---------------- workspace layout ------------------------------------------
// Common head (both paths):
constexpr size_t O_DEG   = 0;              // 2,800,000 -> pad 2,800,128
constexpr size_t O_ROW   = 2800128;        // 2,800,000 -> 5,600,256 (pad)
constexpr size_t O_BLK   = 5600256;        // pad 1024
constexpr size_t O_CSR   = 5601280;        // 44,800,000 -> 50,401,280
constexpr size_t O_B1C   = 50401280;       // 524,288
constexpr size_t O_B2C   = 50925568;       // 1,048,576
constexpr size_t O_WC1T  = 51974144;       // 65,536
constexpr size_t O_W2P   = 52039680;       // 1024
constexpr size_t O_CP    = 52040704;       // 256
constexpr size_t O_B1S   = 52040960;       // 1024
constexpr size_t O_B2S   = 52041984;       // 1024
constexpr size_t O_XB    = 52043008;       // xb bf16 row-major 25,600,000
// CSR-build scratch (dead before convert_x). bcnt FIRST, then the bucket
// buffer sized 896*BCAP*4 = 51,380,224 B.
constexpr size_t O_BCNT  = 52043008;       // 4096 -> 52,047,104
constexpr size_t O_BPK   = 52047104;       // 51,380,224 -> 103,427,328
// FULL path (L1 full means, L2 half means):
constexpr size_t OF_MEAN1 = 77643008;      // 7x100000x128 bf16 = 179,200,000 -> 256,843,008
constexpr size_t OF_HACC1 = 256843008;     // 51,200,000 -> 308,043,008
constexpr size_t OF_H1B   = 52043008;      // 51,200,000 (xb + mean1 head dead) -> 103,243,008
constexpr size_t OF_MEAN2 = 103243008;     // 7x50000x256 bf16 = 179,200,000 -> 282,443,008
constexpr size_t OF_HACC2 = 282443008;     // 51,200,000 -> 333,643,008
constexpr size_t OF_H2B   = 52043008;      // (h1b dead after L2 GEMMs)
constexpr size_t OF_Z1    = 103243008;     // f32 51,200,000 (mean2 dead)
constexpr size_t WS_FULL  = 333643008;
// FALLBACK path (= C8: L1 halves, L2 quarters):
constexpr size_t OQ_MEAN1 = 77643008;      // 7x50000x128 bf16 = 89,600,000
constexpr size_t OQ_HACC1 = 167243008;     // 51,200,000 -> 218,443,008
constexpr size_t OQ_H1B   = 52043008;
constexpr size_t OQ_MEAN2 = 103243008;     // 7x25000x256 bf16 = 89,600,000
constexpr size_t OQ_HACC2 = 192843008;     // 51,200,000 -> 244,043,008
constexpr size_t OQ_H2B   = 52043008;
constexpr size_t OQ_Z1    = 103243008;
constexpr size_t WS_QUART = 244043008;

extern "C" void kernel_launch(void* const* d_in, const int* in_sizes, int n_in,
                              void* d_out, int out_size, void* d_ws, size_t ws_size,
                              hipStream_t stream) {
    (void)in_sizes; (void)n_in;
    const float* features = (const float*)d_in[0];
    const int* edges = (const int*)d_in[1];
    const float* Wself1 = (const float*)d_in[2];
    const float* Wneigh1 = (const float*)d_in[3];
    const float* b1 = (const float*)d_in[4];
    const float* Wself2 = (const float*)d_in[5];
    const float* Wneigh2 = (const float*)d_in[6];
    const float* b2 = (const float*)d_in[7];
    const float* ln_g = (const float*)d_in[8];
    const float* ln_b = (const float*)d_in[9];
    const float* Wc1 = (const float*)d_in[10];
    const float* bc1 = (const float*)d_in[11];
    const float* bn_g = (const float*)d_in[12];
    const float* bn_b = (const float*)d_in[13];
    const float* Wc2 = (const float*)d_in[14];
    const float* bc2 = (const float*)d_in[15];
    float* out = (float*)d_out;
    char* ws = (char*)d_ws;

    if (ws_size < WS_QUART) {
        hipMemsetAsync(d_out, 0, (size_t)out_size * 4, stream);
        return;
    }
    bool full = (ws_size >= WS_FULL);

    int* deg = (int*)(ws + O_DEG);
    int* rowptr = (int*)(ws + O_ROW);
    int* blk = (int*)(ws + O_BLK);
    int* csr = (int*)(ws + O_CSR);
    ushort_t* B1cat = (ushort_t*)(ws + O_B1C);
    ushort_t* B2cat = (ushort_t*)(ws + O_B2C);
    ushort_t* Wc1T = (ushort_t*)(ws + O_WC1T);
    float* W2p = (float*)(ws + O_W2P);
    float* cp = (float*)(ws + O_CP);
    float* b1s = (float*)(ws + O_B1S);
    float* b2s = (float*)(ws + O_B2S);
    ushort_t* xb = (ushort_t*)(ws + O_XB);
    int* bcnt = (int*)(ws + O_BCNT);
    uint* bpack = (uint*)(ws + O_BPK);

    ushort_t* mean1 = (ushort_t*)(ws + (full ? OF_MEAN1 : OQ_MEAN1));
    ushort_t* hacc1 = (ushort_t*)(ws + (full ? OF_HACC1 : OQ_HACC1));
    ushort_t* h1b   = (ushort_t*)(ws + (full ? OF_H1B : OQ_H1B));
    ushort_t* mean2 = (ushort_t*)(ws + (full ? OF_MEAN2 : OQ_MEAN2));
    ushort_t* hacc2 = (ushort_t*)(ws + (full ? OF_HACC2 : OQ_HACC2));
    ushort_t* h2b   = (ushort_t*)(ws + (full ? OF_H2B : OQ_H2B));
    float* z1       = (float*)(ws + (full ? OF_Z1 : OQ_Z1));

    hipMemsetAsync(bcnt, 0, 4096, stream);

    // ---- CSR build (coalesced; scratch dead before convert_x) ----
    binpass_k<<<dim3(391, 7, 1), 256, 0, stream>>>(edges, bcnt, bpack);
    deg_bucket_k<<<896, 1024, 0, stream>>>(bpack, bcnt, deg);
    scan1_k<<<171, 256, 0, stream>>>(deg, rowptr, blk, NREL * NN);
    scan2_k<<<1, 64, 0, stream>>>(blk, 171);
    scan3_k<<<171, 256, 0, stream>>>(rowptr, blk, NREL * NN);
    bucket_sort_k<<<896, 1024, 0, stream>>>(bpack, bcnt, rowptr, csr);

    // ---- weight prep + x -> bf16 ----
    convert_x_k<<<12500, 256, 0, stream>>>(features, xb);
    prep_B1cat_k<<<1025, 256, 0, stream>>>(Wself1, Wneigh1, b1, B1cat, b1s);
    prep_B2cat_k<<<2050, 256, 0, stream>>>(Wself2, Wneigh2, b2, B2cat, b2s);
    prep_cls_k<<<130, 256, 0, stream>>>(Wc1, bn_g, bn_b, Wc2, bc2, Wc1T, W2p, cp);

    if (full) {
        // ---- layer 1: full means; GEMM grid 16*ceil(782/8)=1568 flat ----
        gather_mean_k<1><<<dim3(25000, 7, 1), 256, 0, stream>>>(
            xb, csr, rowptr, deg, mean1, 0, 100000);
        gemm_multi<<<dim3(1568, 1, 1), 256, 0, stream>>>(
            xb, mean1, 128, 7, 0, 100000, B1cat,
            hacc1, 100000, 256, 1024, 1.f / 7.f, b1s, 2);
        ln_relu_b_k<<<25000, 256, 0, stream>>>(hacc1, ln_g, ln_b, h1b);

        // ---- layer 2: 2 halves; GEMM grid 16*ceil(391/8)=784 flat ----
        for (int h = 0; h < 2; ++h) {
            int n0 = h * 50000;
            gather_mean_k<2><<<dim3(12500, 7, 1), 256, 0, stream>>>(
                h1b, csr, rowptr, deg, mean2, n0, 50000);
            gemm_multi<<<dim3(784, 1, 1), 256, 0, stream>>>(
                h1b, mean2, 256, 8, n0, 50000, B2cat,
                hacc2 + (size_t)n0 * 256, 50000, 256, 2048, 1.f / 7.f, b2s, 2);
        }
        ln_relu_b_k<<<25000, 256, 0, stream>>>(hacc2, ln_g + 256, ln_b + 256, h2b);
    } else {
        // ---- fallback (C8 slicing, merged-relation gathers) ----
        for (int h = 0; h < 2; ++h) {
            int n0 = h * 50000;
            gather_mean_k<1><<<dim3(12500, 7, 1), 256, 0, stream>>>(
                xb, csr, rowptr, deg, mean1, n0, 50000);
            gemm_multi<<<dim3(784, 1, 1), 256, 0, stream>>>(
                xb, mean1, 128, 7, n0, 50000, B1cat,
                hacc1 + (size_t)n0 * 256, 50000, 256, 1024, 1.f / 7.f, b1s, 2);
        }
        ln_relu_b_k<<<25000, 256, 0, stream>>>(hacc1, ln_g, ln_b, h1b);

        for (int q = 0; q < 4; ++q) {
            int n0 = q * 25000;
            gather_mean_k<2><<<dim3(6250, 7, 1), 256, 0, stream>>>(
                h1b, csr, rowptr, deg, mean2, n0, 25000);
            gemm_multi<<<dim3(400, 1, 1), 256, 0, stream>>>(
                h1b, mean2, 256, 8, n0, 25000, B2cat,
                hacc2 + (size_t)n0 * 256, 25000, 256, 2048, 1.f / 7.f, b2s, 2);
        }
        ln_relu_b_k<<<25000, 256, 0, stream>>>(hacc2, ln_g + 256, ln_b + 256, h2b);
    }

    // ---- classifier (N=128: single column block, p = blockIdx.x) ----
    gemm_multi<<<dim3(782, 1, 1), 256, 0, stream>>>(
        h2b, nullptr, 256, 8, 0, 0, Wc1T, z1, NN, 128, 256, 1.f, bc1, 4);
    final_k<<<25000, 256, 0, stream>>>(z1, W2p, cp, out);
}